// Round 1
// baseline (128.222 us; speedup 1.0000x reference)
//
#include <hip/hip_runtime.h>

typedef __attribute__((ext_vector_type(8))) short   bf16x8;
typedef __attribute__((ext_vector_type(4))) float   f32x4;
typedef __attribute__((ext_vector_type(4))) unsigned int u32x4;

#define HT    16      // output rows per block
#define WSPAN 66      // staged w columns: 64 + 2 halo

__device__ __forceinline__ unsigned short f2bf(float f) {
    union { float f; unsigned u; } v; v.f = f;
    unsigned u = v.u;
    u += 0x7FFFu + ((u >> 16) & 1u);   // RNE
    return (unsigned short)(u >> 16);
}

__global__ __launch_bounds__(256, 2)
void conv3x3_mfma(const float* __restrict__ x, const float* __restrict__ wk,
                  float* __restrict__ out) {
    const int hb = blockIdx.x, wh = blockIdx.y, n = blockIdx.z;
    const int H0 = hb * HT, W0 = wh * 64;
    const int tid  = threadIdx.x;
    const int lane = tid & 63, wid = tid >> 6;
    const int lq = lane >> 4, lr = lane & 15;
    const int Pb = wid * 16;                    // wave's pixel base

    // 3 row-slots x 66 w x 32 c (bf16) ; each (slot,w) row = 64B = 4 x u32x4
    __shared__ u32x4 lds[3 * WSPAN * 4];

    // ---------------- weights -> registers (A fragments) ----------------
    // A[o][k=c] for tap (ki,kj): lane holds rows o=16t+lr, k = 8*lq + j.
    // Raw buffer index: ((c*3+ki)*3+kj)*64 + o   (reshape quirk).
    bf16x8 wA[4][9];
    #pragma unroll
    for (int t = 0; t < 4; ++t) {
        #pragma unroll
        for (int p = 0; p < 9; ++p) {
            const int ki = p / 3, kj = p % 3;
            union { bf16x8 v; unsigned short s[8]; } u;
            #pragma unroll
            for (int j = 0; j < 8; ++j) {
                const int c = lq * 8 + j;
                u.s[j] = f2bf(wk[((c * 3 + ki) * 3 + kj) * 64 + t * 16 + lr]);
            }
            wA[t][p] = u.v;
        }
    }

    // ---------------- staging helpers ----------------
    // task A: every thread: (cb = tid>>6, w' = tid&63)
    // task B: threads 0..7: (cb = tid>>1, w' = 64 + (tid&1))  -> covers 4cb x 66w
    const int cb0 = tid >> 6, wq0 = tid & 63;
    const bool hasB = (tid < 8);
    const int cb1 = tid >> 1, wq1 = 64 + (tid & 1);

    auto issue_loads = [&](int rg, int cb, int wq, float (&dst)[8]) {
        const int wg = W0 - 1 + wq;
        const bool ok = ((unsigned)rg < 128u) && ((unsigned)wg < 128u);
        const float* p = x + (((n * 32 + cb * 8) * 128 + rg) * 128 + wg);
        #pragma unroll
        for (int j = 0; j < 8; ++j)
            dst[j] = ok ? p[j * 16384] : 0.0f;   // stride = H*W between channels
    };
    auto lds_write = [&](int slot, int cb, int wq, const float (&src)[8]) {
        const int f = (wq ^ (wq >> 2)) & 3;      // 16B-granular XOR swizzle
        u32x4 pk;
        pk[0] = (unsigned)f2bf(src[0]) | ((unsigned)f2bf(src[1]) << 16);
        pk[1] = (unsigned)f2bf(src[2]) | ((unsigned)f2bf(src[3]) << 16);
        pk[2] = (unsigned)f2bf(src[4]) | ((unsigned)f2bf(src[5]) << 16);
        pk[3] = (unsigned)f2bf(src[6]) | ((unsigned)f2bf(src[7]) << 16);
        lds[(slot * WSPAN + wq) * 4 + (cb ^ f)] = pk;
    };
    auto frag_read = [&](int slot, int wq) -> bf16x8 {
        const int f = (wq ^ (wq >> 2)) & 3;
        union { u32x4 u; bf16x8 v; } cv;
        cv.u = lds[(slot * WSPAN + wq) * 4 + (lq ^ f)];
        return cv.v;
    };

    // ---------------- accumulators ----------------
    f32x4 acc[3][4];
    const f32x4 zero = {0.f, 0.f, 0.f, 0.f};
    #pragma unroll
    for (int a = 0; a < 3; ++a)
        #pragma unroll
        for (int t = 0; t < 4; ++t) acc[a][t] = zero;

    // ---------------- prologue: stage row H0-1 (slot 0), preload row H0 ----------------
    float stA[8], stB[8];
    issue_loads(H0 - 1, cb0, wq0, stA);
    if (hasB) issue_loads(H0 - 1, cb1, wq1, stB);
    lds_write(0, cb0, wq0, stA);
    if (hasB) lds_write(0, cb1, wq1, stB);
    issue_loads(H0, cb0, wq0, stA);
    if (hasB) issue_loads(H0, cb1, wq1, stB);
    __syncthreads();

    // ---------------- main loop over staged rows r = H0-1 .. H0+16 ----------------
    #pragma unroll
    for (int rho = 0; rho < 18; ++rho) {
        const int slot = rho % 3;

        // 1. B-fragments for this row (3 taps kj), bank-conflict-free b128
        bf16x8 fb[3];
        #pragma unroll
        for (int kj = 0; kj < 3; ++kj)
            fb[kj] = frag_read(slot, Pb + lr + kj);

        // 2. write previously-loaded row r+1 into slot (rho+1)%3
        if (rho <= 16) {
            lds_write((rho + 1) % 3, cb0, wq0, stA);
            if (hasB) lds_write((rho + 1) % 3, cb1, wq1, stB);
        }
        // 3. issue global loads for row r+2 (land next iter)
        if (rho <= 15) {
            issue_loads(H0 + rho + 1, cb0, wq0, stA);
            if (hasB) issue_loads(H0 + rho + 1, cb1, wq1, stB);
        }

        // 4. MFMAs: row r contributes to h = H0 + rho - ki  (valid: 0<=rho-ki<=15)
        #pragma unroll
        for (int kj = 0; kj < 3; ++kj) {
            #pragma unroll
            for (int ki = 0; ki < 3; ++ki) {
                if (rho - ki < 0 || rho - ki > 15) continue;
                const int a = (rho - ki + 1) % 3;     // static
                #pragma unroll
                for (int t = 0; t < 4; ++t)
                    acc[a][t] = __builtin_amdgcn_mfma_f32_16x16x32_bf16(
                        wA[t][ki * 3 + kj], fb[kj], acc[a][t], 0, 0, 0);
            }
        }

        // 5. h = H0 + rho - 2 is complete: store and reset its slot
        if (rho >= 2) {
            const int a = (rho - 1) % 3;              // static
            const int h = H0 + rho - 2;
            #pragma unroll
            for (int t = 0; t < 4; ++t) {
                #pragma unroll
                for (int j = 0; j < 4; ++j) {
                    const int o = t * 16 + lq * 4 + j;   // D: row=(lane>>4)*4+reg
                    out[((n * 64 + o) * 128 + h) * 128 + (W0 + Pb + lr)] = acc[a][t][j];
                }
                acc[a][t] = zero;
            }
        }
        __syncthreads();
    }
}

extern "C" void kernel_launch(void* const* d_in, const int* in_sizes, int n_in,
                              void* d_out, int out_size, void* d_ws, size_t ws_size,
                              hipStream_t stream) {
    const float* x  = (const float*)d_in[0];
    const float* wk = (const float*)d_in[1];
    float* out = (float*)d_out;
    dim3 grid(8, 2, 32);   // hb, wh, n
    dim3 block(256);
    conv3x3_mfma<<<grid, block, 0, stream>>>(x, wk, out);
}

// Round 2
// 69.310 us; speedup vs baseline: 1.8500x; 1.8500x over previous
//
#include <hip/hip_runtime.h>

typedef __attribute__((ext_vector_type(8))) short   bf16x8;
typedef __attribute__((ext_vector_type(4))) float   f32x4;
typedef __attribute__((ext_vector_type(4))) unsigned int u32x4;

#define HT    16      // output rows per block
#define WSPAN 66      // staged w columns: 64 + 2 halo
#define NROWS 18      // HT + 2 staged rows

__device__ __forceinline__ unsigned short f2bf(float f) {
    union { float f; unsigned u; } v; v.f = f;
    unsigned u = v.u;
    u += 0x7FFFu + ((u >> 16) & 1u);   // RNE
    return (unsigned short)(u >> 16);
}

__global__ __launch_bounds__(256, 2)
void conv3x3_mfma(const float* __restrict__ x, const float* __restrict__ wk,
                  float* __restrict__ out) {
    const int hb = blockIdx.x, wh = blockIdx.y, n = blockIdx.z;
    const int H0 = hb * HT, W0 = wh * 64;
    const int tid  = threadIdx.x;
    const int lane = tid & 63, wid = tid >> 6;
    const int lq = lane >> 4, lr = lane & 15;

    // 4 row-slots x 66 w x 32 c (bf16); each (slot,w) row = 64B = 4 x u32x4
    __shared__ u32x4 lds[4 * WSPAN * 4];

    // ---------------- weights -> registers (A fragments) ----------------
    // Wave `wid` owns och tile t=wid (16 channels). A[o][k=c] for tap (ki,kj):
    // lane holds row o = wid*16 + lr, k = 8*lq + j.
    // Raw buffer index: ((c*3+ki)*3+kj)*64 + o   (reshape quirk).
    bf16x8 wA[9];
    #pragma unroll
    for (int p = 0; p < 9; ++p) {
        const int ki = p / 3, kj = p % 3;
        union { bf16x8 v; unsigned short s[8]; } u;
        #pragma unroll
        for (int j = 0; j < 8; ++j) {
            const int c = lq * 8 + j;
            u.s[j] = f2bf(wk[((c * 3 + ki) * 3 + kj) * 64 + wid * 16 + lr]);
        }
        wA[p] = u.v;
    }

    // ---------------- staging helpers ----------------
    // task A: every thread: (cb = tid>>6, w' = tid&63)
    // task B: threads 0..7: (cb = tid>>1, w' = 64 + (tid&1))  -> covers 4cb x 2w
    const int cb0 = tid >> 6, wq0 = tid & 63;
    const bool hasB = (tid < 8);
    const int cb1 = tid >> 1, wq1 = 64 + (tid & 1);

    auto issue_loads = [&](int rg, int cb, int wq, float (&dst)[8]) {
        const int wg = W0 - 1 + wq;
        const bool ok = ((unsigned)rg < 128u) && ((unsigned)wg < 128u);
        const float* p = x + (((n * 32 + cb * 8) * 128 + rg) * 128 + wg);
        #pragma unroll
        for (int j = 0; j < 8; ++j)
            dst[j] = ok ? p[j * 16384] : 0.0f;   // stride = H*W between channels
    };
    auto lds_write = [&](int slot, int cb, int wq, const float (&src)[8]) {
        const int f = (wq ^ (wq >> 2)) & 3;      // 16B-granular XOR swizzle
        u32x4 pk;
        pk[0] = (unsigned)f2bf(src[0]) | ((unsigned)f2bf(src[1]) << 16);
        pk[1] = (unsigned)f2bf(src[2]) | ((unsigned)f2bf(src[3]) << 16);
        pk[2] = (unsigned)f2bf(src[4]) | ((unsigned)f2bf(src[5]) << 16);
        pk[3] = (unsigned)f2bf(src[6]) | ((unsigned)f2bf(src[7]) << 16);
        lds[(slot * WSPAN + wq) * 4 + (cb ^ f)] = pk;
    };
    auto frag_read = [&](int slot, int wq) -> bf16x8 {
        const int f = (wq ^ (wq >> 2)) & 3;
        union { u32x4 u; bf16x8 v; } cv;
        cv.u = lds[(slot * WSPAN + wq) * 4 + (lq ^ f)];
        return cv.v;
    };

    // ---------------- accumulators: 3-row ring x 4 pixel groups ----------------
    f32x4 acc[3][4];
    const f32x4 zero = {0.f, 0.f, 0.f, 0.f};
    #pragma unroll
    for (int a = 0; a < 3; ++a)
        #pragma unroll
        for (int pg = 0; pg < 4; ++pg) acc[a][pg] = zero;

    // per-thread output base: o = wid*16 + lq*4 (+j), w = W0 + lr (+pg*16)
    float* obase = out + (((n * 64 + wid * 16 + lq * 4) * 128) * 128) + W0 + lr;

    // ---------------- prologue: 2-row-deep pipeline fill ----------------
    // staged row rho <-> global row H0-1+rho ; reg buffer parity rho%2
    float bufA[2][8], bufB[2][8];
    issue_loads(H0 - 1, cb0, wq0, bufA[0]);
    if (hasB) issue_loads(H0 - 1, cb1, wq1, bufB[0]);
    issue_loads(H0, cb0, wq0, bufA[1]);
    if (hasB) issue_loads(H0, cb1, wq1, bufB[1]);

    lds_write(0, cb0, wq0, bufA[0]);
    if (hasB) lds_write(0, cb1, wq1, bufB[0]);
    issue_loads(H0 + 1, cb0, wq0, bufA[0]);            // row rho=2
    if (hasB) issue_loads(H0 + 1, cb1, wq1, bufB[0]);

    lds_write(1, cb0, wq0, bufA[1]);
    if (hasB) lds_write(1, cb1, wq1, bufB[1]);
    issue_loads(H0 + 2, cb0, wq0, bufA[1]);            // row rho=3
    if (hasB) issue_loads(H0 + 2, cb1, wq1, bufB[1]);
    __syncthreads();

    // ---------------- main loop over staged rows rho = 0..17 ----------------
    #pragma unroll
    for (int rho = 0; rho < NROWS; ++rho) {
        const int slot = rho % 4;

        // 1. compute: this staged row feeds h = H0 + rho - ki
        #pragma unroll
        for (int pg = 0; pg < 4; ++pg) {
            #pragma unroll
            for (int kj = 0; kj < 3; ++kj) {
                const bf16x8 fb = frag_read(slot, pg * 16 + lr + kj);
                #pragma unroll
                for (int ki = 0; ki < 3; ++ki) {
                    if (rho - ki < 0 || rho - ki > 15) continue;
                    const int a = (rho - ki + 1) % 3;     // static under unroll
                    acc[a][pg] = __builtin_amdgcn_mfma_f32_16x16x32_bf16(
                        wA[ki * 3 + kj], fb, acc[a][pg], 0, 0, 0);
                }
            }
        }

        // 2. write row rho+2 (loads issued 2 iters ago) into slot (rho+2)%4
        if (rho + 2 < NROWS) {
            lds_write((rho + 2) % 4, cb0, wq0, bufA[rho % 2]);
            if (hasB) lds_write((rho + 2) % 4, cb1, wq1, bufB[rho % 2]);
        }
        // 3. issue global loads for row rho+4 into the freed buffer
        if (rho + 4 < NROWS) {
            issue_loads(H0 + rho + 3, cb0, wq0, bufA[rho % 2]);
            if (hasB) issue_loads(H0 + rho + 3, cb1, wq1, bufB[rho % 2]);
        }

        // 4. h = H0 + rho - 2 is complete: store and reset its acc slot
        if (rho >= 2) {
            const int a = (rho - 1) % 3;                  // static under unroll
            const int h = H0 + rho - 2;
            #pragma unroll
            for (int pg = 0; pg < 4; ++pg) {
                #pragma unroll
                for (int j = 0; j < 4; ++j)
                    obase[(j * 128 + h) * 128 + pg * 16] = acc[a][pg][j];
                acc[a][pg] = zero;
            }
        }
        __syncthreads();
    }
}

extern "C" void kernel_launch(void* const* d_in, const int* in_sizes, int n_in,
                              void* d_out, int out_size, void* d_ws, size_t ws_size,
                              hipStream_t stream) {
    const float* x  = (const float*)d_in[0];
    const float* wk = (const float*)d_in[1];
    float* out = (float*)d_out;
    dim3 grid(8, 2, 32);   // hb, wh, n
    dim3 block(256);
    conv3x3_mfma<<<grid, block, 0, stream>>>(x, wk, out);
}

// Round 3
// 62.813 us; speedup vs baseline: 2.0413x; 1.1034x over previous
//
#include <hip/hip_runtime.h>

typedef __attribute__((ext_vector_type(8))) short   bf16x8;
typedef __attribute__((ext_vector_type(4))) float   f32x4;
typedef __attribute__((ext_vector_type(4))) unsigned int u32x4;

#define HT    8       // output rows per block
#define WSPAN 66      // staged w columns: 64 + 2 halo
#define NROWS (HT + 2)

__device__ __forceinline__ unsigned short f2bf(float f) {
    union { float f; unsigned u; } v; v.f = f;
    unsigned u = v.u;
    u += 0x7FFFu + ((u >> 16) & 1u);   // RNE
    return (unsigned short)(u >> 16);
}

__global__ __launch_bounds__(256, 2)
void conv3x3_mfma(const float* __restrict__ x, const float* __restrict__ wk,
                  float* __restrict__ out) {
    const int hb = blockIdx.x, wh = blockIdx.y, n = blockIdx.z;
    const int H0 = hb * HT, W0 = wh * 64;
    const int tid  = threadIdx.x;
    const int lane = tid & 63, wid = tid >> 6;
    const int lq = lane >> 4, lr = lane & 15;

    // 4 row-slots x 66 w x 32 c (bf16); each (slot,w) row = 64B = 4 x u32x4
    __shared__ u32x4 lds[4 * WSPAN * 4];

    // ---- weights -> registers: wave `wid` owns och tile [wid*16, wid*16+16) ----
    // Raw buffer index: ((c*3+ki)*3+kj)*64 + o   (reshape quirk).
    bf16x8 wA[9];
    #pragma unroll
    for (int p = 0; p < 9; ++p) {
        const int ki = p / 3, kj = p % 3;
        union { bf16x8 v; unsigned short s[8]; } u;
        #pragma unroll
        for (int j = 0; j < 8; ++j) {
            const int c = lq * 8 + j;
            u.s[j] = f2bf(wk[((c * 3 + ki) * 3 + kj) * 64 + wid * 16 + lr]);
        }
        wA[p] = u.v;
    }

    // ---- staging tasks ----
    // task A: every thread: (cb = tid>>6, wq = tid&63)
    // task B: threads 0..7: (cb = tid>>1, wq = 64+(tid&1))
    const int cb0 = tid >> 6, wq0 = tid & 63;
    const bool hasB = (tid < 8);
    const int cb1 = tid >> 1, wq1 = 64 + (tid & 1);

    auto issue_loads = [&](int rg, int cb, int wq, float (&dst)[8]) {
        const int wg = W0 - 1 + wq;
        const bool ok = ((unsigned)rg < 128u) && ((unsigned)wg < 128u);
        const float* p = x + (((n * 32 + cb * 8) * 128 + rg) * 128 + wg);
        #pragma unroll
        for (int j = 0; j < 8; ++j)
            dst[j] = ok ? p[j * 16384] : 0.0f;   // channel stride = H*W
    };
    // swizzle f=(wq>>1)&3: every 8 consecutive lanes hit 8 distinct bank-quads
    // for BOTH writes (wq consecutive in tid) and reads (wq consecutive in lr).
    auto lds_write = [&](int slot, int cb, int wq, const float (&src)[8]) {
        const int f = (wq >> 1) & 3;
        u32x4 pk;
        pk[0] = (unsigned)f2bf(src[0]) | ((unsigned)f2bf(src[1]) << 16);
        pk[1] = (unsigned)f2bf(src[2]) | ((unsigned)f2bf(src[3]) << 16);
        pk[2] = (unsigned)f2bf(src[4]) | ((unsigned)f2bf(src[5]) << 16);
        pk[3] = (unsigned)f2bf(src[6]) | ((unsigned)f2bf(src[7]) << 16);
        lds[(slot * WSPAN + wq) * 4 + (cb ^ f)] = pk;
    };
    auto frag_read = [&](int slot, int wq) -> bf16x8 {
        const int f = (wq >> 1) & 3;
        union { u32x4 u; bf16x8 v; } cv;
        cv.u = lds[(slot * WSPAN + wq) * 4 + (lq ^ f)];
        return cv.v;
    };

    // ---- accumulators: 3-row ring x 4 pixel groups ----
    f32x4 acc[3][4];
    const f32x4 zero = {0.f, 0.f, 0.f, 0.f};
    #pragma unroll
    for (int a = 0; a < 3; ++a)
        #pragma unroll
        for (int pg = 0; pg < 4; ++pg) acc[a][pg] = zero;

    // per-thread output base: o = wid*16 + lq*4 (+j), w = W0 + lr (+pg*16)
    float* obase = out + (((n * 64 + wid * 16 + lq * 4) * 128) * 128) + W0 + lr;

    // ---- prologue: stage rows 0,1 (global H0-1, H0); preload row 2 ----
    float bufA[8], bufB[8];
    issue_loads(H0 - 1, cb0, wq0, bufA);
    if (hasB) issue_loads(H0 - 1, cb1, wq1, bufB);
    lds_write(0, cb0, wq0, bufA);
    if (hasB) lds_write(0, cb1, wq1, bufB);
    issue_loads(H0, cb0, wq0, bufA);
    if (hasB) issue_loads(H0, cb1, wq1, bufB);
    lds_write(1, cb0, wq0, bufA);
    if (hasB) lds_write(1, cb1, wq1, bufB);
    issue_loads(H0 + 1, cb0, wq0, bufA);
    if (hasB) issue_loads(H0 + 1, cb1, wq1, bufB);
    __syncthreads();

    // ---- one fully-static row iteration (RHO is a literal) ----
    // staged row RHO (global H0-1+RHO) lives in slot RHO%4; contributes to
    // output rows h = H0+RHO-ki; row h completes & stores at RHO = h-H0+2.
#define ROW(RHO)                                                              \
    {                                                                         \
        _Pragma("unroll")                                                     \
        for (int pg = 0; pg < 4; ++pg) {                                      \
            _Pragma("unroll")                                                 \
            for (int kj = 0; kj < 3; ++kj) {                                  \
                const bf16x8 fb = frag_read((RHO) % 4, pg * 16 + lr + kj);    \
                _Pragma("unroll")                                             \
                for (int ki = 0; ki < 3; ++ki) {                              \
                    if ((RHO) - ki < 0 || (RHO) - ki > HT - 1) continue;      \
                    acc[((RHO) - ki + 1) % 3][pg] =                           \
                        __builtin_amdgcn_mfma_f32_16x16x32_bf16(              \
                            wA[ki * 3 + kj], fb,                              \
                            acc[((RHO) - ki + 1) % 3][pg], 0, 0, 0);          \
                }                                                             \
            }                                                                 \
        }                                                                     \
        if ((RHO) + 2 < NROWS) {                                              \
            lds_write(((RHO) + 2) % 4, cb0, wq0, bufA);                       \
            if (hasB) lds_write(((RHO) + 2) % 4, cb1, wq1, bufB);             \
        }                                                                     \
        if ((RHO) + 3 < NROWS) {                                              \
            issue_loads(H0 + (RHO) + 2, cb0, wq0, bufA);                      \
            if (hasB) issue_loads(H0 + (RHO) + 2, cb1, wq1, bufB);            \
        }                                                                     \
        if ((RHO) >= 2) {                                                     \
            const int h = H0 + (RHO) - 2;                                     \
            _Pragma("unroll")                                                 \
            for (int pg = 0; pg < 4; ++pg) {                                  \
                _Pragma("unroll")                                             \
                for (int j = 0; j < 4; ++j)                                   \
                    obase[(j * 128 + h) * 128 + pg * 16] =                    \
                        acc[((RHO) - 1) % 3][pg][j];                          \
                acc[((RHO) - 1) % 3][pg] = zero;                              \
            }                                                                 \
        }                                                                     \
        __syncthreads();                                                      \
    }

    ROW(0) ROW(1) ROW(2) ROW(3) ROW(4) ROW(5) ROW(6) ROW(7) ROW(8) ROW(9)
#undef ROW
}

extern "C" void kernel_launch(void* const* d_in, const int* in_sizes, int n_in,
                              void* d_out, int out_size, void* d_ws, size_t ws_size,
                              hipStream_t stream) {
    const float* x  = (const float*)d_in[0];
    const float* wk = (const float*)d_in[1];
    float* out = (float*)d_out;
    dim3 grid(16, 2, 32);   // hb, wh, n  -> 1024 blocks = 4 per CU
    dim3 block(256);
    conv3x3_mfma<<<grid, block, 0, stream>>>(x, wk, out);
}